// Round 5
// baseline (70.887 us; speedup 1.0000x reference)
//
#include <hip/hip_runtime.h>
#include <math.h>

// BoundsChecker: nearest-point-on-closed-path + Newton refine + frame/width
// outputs. ONE kernel. 16 LANES PER QUERY, tiny (2 KB) LDS, max occupancy.
//
// Round-4 post-mortem: staging the full 64 KB refline into LDS per block
// (a) capped occupancy at 2 blocks/CU (16/32 waves) and (b) serialized every
// block behind a 64 KB stage+barrier, while each query only ever reads ~70
// of the 8192 points. Fix: keep only the 256-point coarse grid in LDS (2 KB);
// fine scan + Newton read ref directly from global (64 KB, L1/L2-resident);
// LPQ 8->16 so grid = 2048 blocks = 8 blocks/CU = 32 waves/CU (100% wave
// capacity, forced via __launch_bounds__(256,8)). Scattered global reads were
// round-2's killer at 2 waves/CU -- the cure is TLP, not LDS.
//
// Inputs: positions[B,2] f32, refline_points[N,2] f32, left_widths[N] f32,
//         right_widths[N] f32, newton_iterations (int scalar in device mem).
// Output (flat concat, f32): r[B], point[B,2], tang[B,2], norm[B,2],
//         deltas[B,2], normal_projections[B], left[B], right[B] (12*B total).

#define DR_SAMP 1.0f
#define MAX_STEP 1.0f
#define TERM_EPS 1e-4f
#define TERM_DELTA_EPS 1e-2f

#define COARSE 32      // coarse stride (samples)
#define WIN 64         // fine window width (coarse best provably within +-17)
#define BLK 256
#define LPQ 16         // lanes per query -> 524288 threads, 2048 blocks

// Packed argmin key: top 19 bits of float(d2) | 13-bit index (N <= 8192).
// d2 >= 0 so float bits order as unsigned. Near-tie mis-ordering is absorbed
// by Newton (passed rounds 1-4 with absmax 0.031).
#define IDXBITS 13
#define IDXMASK ((1u << IDXBITS) - 1u)
#define KEYMASK (~IDXMASK)

__device__ __forceinline__ unsigned int pack_key(float d2, int i) {
    return (__float_as_uint(d2) & KEYMASK) | (unsigned int)i;
}

__device__ __forceinline__ int wrapN(int i, int N) {
    return (i < 0) ? i + N : ((i >= N) ? i - N : i);
}

// butterfly min over each aligned 16-lane group (xor 1,2,4,8 stays in-group)
__device__ __forceinline__ unsigned int grp16_min(unsigned int k) {
    k = min(k, (unsigned int)__shfl_xor((int)k, 1));
    k = min(k, (unsigned int)__shfl_xor((int)k, 2));
    k = min(k, (unsigned int)__shfl_xor((int)k, 4));
    k = min(k, (unsigned int)__shfl_xor((int)k, 8));
    return k;
}

__global__ __launch_bounds__(BLK, 8) void bc_fused(
    const float* __restrict__ pos, const float* __restrict__ ref,
    const float* __restrict__ lw, const float* __restrict__ rw,
    const int* __restrict__ nit_p, float* __restrict__ out, int B, int N)
{
    __shared__ float2 scoarse[512];   // up to NC=512; 4 KB max (N<=16384)

    const float2* __restrict__ ref2 = (const float2*)ref;
    int NC = N / COARSE;  // 256 for N=8192

    // ---- stage coarse grid -> LDS: one strided gather pass (L2-hot) -------
    for (int t = threadIdx.x; t < NC; t += BLK)
        scoarse[t] = ref2[t * COARSE];
    __syncthreads();

    int gtid = blockIdx.x * BLK + threadIdx.x;
    int q = gtid / LPQ;               // 16 consecutive lanes share a query
    int l = threadIdx.x & (LPQ - 1);  // lane-in-group
    if (q >= B) return;

    const float L = (float)N * DR_SAMP;
    float px = pos[2 * q], py = pos[2 * q + 1];  // group-broadcast loads

    // ---- coarse scan: lane l takes m = l, l+16, ... (16 cands/lane) -------
    // Per instruction the wave reads 16 distinct scoarse entries, 4-way
    // same-address broadcast -> conflict-free.
    unsigned int c0 = 0xFFFFFFFFu, c1 = 0xFFFFFFFFu;
    unsigned int c2 = 0xFFFFFFFFu, c3 = 0xFFFFFFFFu;
#define CANDC(pt, ii, acc)                                   \
    {                                                        \
        float dx_ = px - (pt).x, dy_ = py - (pt).y;          \
        float d2_ = fmaf(dx_, dx_, dy_ * dy_);               \
        acc = min(acc, pack_key(d2_, (ii)));                 \
    }
    for (int m = l; m + 3 * LPQ < NC; m += 4 * LPQ) {
        float2 a0 = scoarse[m];
        float2 a1 = scoarse[m + LPQ];
        float2 a2 = scoarse[m + 2 * LPQ];
        float2 a3 = scoarse[m + 3 * LPQ];
        CANDC(a0, m * COARSE, c0)
        CANDC(a1, (m + LPQ) * COARSE, c1)
        CANDC(a2, (m + 2 * LPQ) * COARSE, c2)
        CANDC(a3, (m + 3 * LPQ) * COARSE, c3)
    }
#undef CANDC
    int jc = (int)(grp16_min(min(min(c0, c1), min(c2, c3))) & IDXMASK);

    // ---- fine exact scan: 64-wide window, 4 cands/lane, global (L1/L2) ----
    unsigned int fbest = 0xFFFFFFFFu;
    int base = jc - (WIN / 2 - 1);
#pragma unroll
    for (int t = 0; t < WIN / LPQ; ++t) {   // 4 iterations
        int i0 = wrapN(base + l + t * LPQ, N);
        float2 p0v = ref2[i0];
        float dx0 = px - p0v.x, dy0 = py - p0v.y;
        fbest = min(fbest, pack_key(fmaf(dx0, dx0, dy0 * dy0), i0));
    }
    fbest = grp16_min(fbest);
    float r = (float)(int)(fbest & IDXMASK) * DR_SAMP;

    // ---- Newton refinement: replicated across the 16 group lanes ----------
    // (identical inputs -> identical result; global reads hit L1/L2)
    int niter = nit_p[0];
    bool done = false;
    for (int it = 0; it < niter; ++it) {
        float fu = floorf(r);
        int i0 = (int)fu;
        if (i0 >= N) i0 -= N;
        int i1 = i0 + 1;
        if (i1 >= N) i1 -= N;
        float frac = r - fu;
        float2 p0 = ref2[i0];
        float2 p1 = ref2[i1];
        float ex = p1.x - p0.x, ey = p1.y - p0.y;
        float ptx = fmaf(frac, ex, p0.x);
        float pty = fmaf(frac, ey, p0.y);
        float inv = rsqrtf(fmaf(ex, ex, ey * ey));
        float tx = ex * inv, ty = ey * inv;
        float dx = px - ptx, dy = py - pty;
        float fprime = -(dx * tx + dy * ty);
        float step = fminf(fmaxf(-fprime, -MAX_STEP), MAX_STEP);
        if (!done) {
            r += step;  // step in [-1,1] => r stays in (-1, L+1)
            if (r >= L) r -= L;
            if (r < 0.0f) r += L;
        }
        done = done || (fabsf(fprime) < TERM_EPS) || (fabsf(step) < TERM_DELTA_EPS);
    }

    // ---- final eval + outputs (lane 0 of each 16-lane group stores) -------
    if (l != 0) return;

    float fu = floorf(r);
    int i0 = (int)fu;
    if (i0 >= N) i0 -= N;
    int i1 = i0 + 1;
    if (i1 >= N) i1 -= N;
    float frac = r - fu;
    float2 p0 = ref2[i0];
    float2 p1 = ref2[i1];
    float ex = p1.x - p0.x, ey = p1.y - p0.y;
    float ptx = fmaf(frac, ex, p0.x);
    float pty = fmaf(frac, ey, p0.y);
    float inv = rsqrtf(fmaf(ex, ex, ey * ey));
    float tx = ex * inv;
    float ty = ey * inv;
    float nx = -ty, ny = tx;
    float dx = px - ptx, dy = py - pty;
    float proj = dx * nx + dy * ny;
    float lv = lw[i0] * (1.0f - frac) + lw[i1] * frac;   // L2-hot 32 KB arrays
    float rv = rw[i0] * (1.0f - frac) + rw[i1] * frac;

    out[q] = r;
    *(float2*)(out + B + 2 * q)     = make_float2(ptx, pty);
    *(float2*)(out + 3 * B + 2 * q) = make_float2(tx, ty);
    *(float2*)(out + 5 * B + 2 * q) = make_float2(nx, ny);
    *(float2*)(out + 7 * B + 2 * q) = make_float2(dx, dy);
    out[9 * B + q]  = proj;
    out[10 * B + q] = lv;
    out[11 * B + q] = rv;
}

extern "C" void kernel_launch(void* const* d_in, const int* in_sizes, int n_in,
                              void* d_out, int out_size, void* d_ws, size_t ws_size,
                              hipStream_t stream) {
    const float* pos = (const float*)d_in[0];
    const float* ref = (const float*)d_in[1];
    const float* lw  = (const float*)d_in[2];
    const float* rw  = (const float*)d_in[3];
    const int*   nit = (const int*)d_in[4];
    int B = in_sizes[0] / 2;
    int N = in_sizes[1] / 2;
    float* out = (float*)d_out;

    // 16 lanes/query: B*16 threads, BLK=256 -> 2048 blocks = 8 blocks/CU
    // (2 KB LDS, VGPR<=64 via launch_bounds) = 32 waves/CU = full capacity.
    long long threads = (long long)B * LPQ;
    int nb = (int)((threads + BLK - 1) / BLK);
    bc_fused<<<nb, BLK, 0, stream>>>(pos, ref, lw, rw, nit, out, B, N);
}

// Round 6
// 70.780 us; speedup vs baseline: 1.0015x; 1.0015x over previous
//
#include <hip/hip_runtime.h>
#include <math.h>

// BoundsChecker: nearest-point-on-closed-path + Newton refine + frame/width
// outputs. Pack kernel (builds float4-packed lookup tables in d_ws) + main
// kernel (16 lanes/query, NO LDS, no barrier).
//
// Round-5 post-mortem: occupancy doubling was neutral -> kernel is bound by
// per-CU memory-instruction throughput (instr count x line splits), not TLP:
// r5's per-block scoarse staging was 256 fully-uncoalesced 256B-strided
// gathers x 2048 blocks, and Newton/fine scans issued 2 loads per point-pair.
// Fixes: (1) pack kernel writes coarse4 (2 KB, L1-resident, read directly --
// staging+barrier deleted), (2) pairs[i]=(ref[i],ref[i+1 mod N]) float4 --
// Newton/fine/epilogue get both points in ONE 16B load and drop the i1 wrap,
// (3) width pairs packed as float4 (4 gathers -> 1).
//
// Inputs: positions[B,2] f32, refline_points[N,2] f32, left_widths[N] f32,
//         right_widths[N] f32, newton_iterations (int scalar in device mem).
// Output (flat concat, f32): r[B], point[B,2], tang[B,2], norm[B,2],
//         deltas[B,2], normal_projections[B], left[B], right[B] (12*B total).

#define DR_SAMP 1.0f
#define MAX_STEP 1.0f
#define TERM_EPS 1e-4f
#define TERM_DELTA_EPS 1e-2f

#define COARSE 32      // coarse stride (samples)
#define WIN 64         // fine window width (coarse best provably within +-17)
#define BLK 256
#define LPQ 16         // lanes per query -> B*16 threads, 2048 blocks

// Packed argmin key: top 19 bits of float(d2) | 13-bit index (N <= 8192).
// d2 >= 0 so float bits order as unsigned. Near-tie mis-ordering is absorbed
// by Newton (passed rounds 1-5 with absmax 0.031).
#define IDXBITS 13
#define IDXMASK ((1u << IDXBITS) - 1u)
#define KEYMASK (~IDXMASK)

__device__ __forceinline__ unsigned int pack_key(float d2, int i) {
    return (__float_as_uint(d2) & KEYMASK) | (unsigned int)i;
}

__device__ __forceinline__ int wrapN(int i, int N) {
    return (i < 0) ? i + N : ((i >= N) ? i - N : i);
}

// butterfly min over each aligned 16-lane group (xor 1,2,4,8 stays in-group)
__device__ __forceinline__ unsigned int grp16_min(unsigned int k) {
    k = min(k, (unsigned int)__shfl_xor((int)k, 1));
    k = min(k, (unsigned int)__shfl_xor((int)k, 2));
    k = min(k, (unsigned int)__shfl_xor((int)k, 4));
    k = min(k, (unsigned int)__shfl_xor((int)k, 8));
    return k;
}

// ---- pack kernel: build float4 lookup tables in d_ws --------------------
// pairs[i]   = (ref[i].x, ref[i].y, ref[i+1].x, ref[i+1].y)   (i+1 mod N)
// wpair[i]   = (lw[i], lw[i+1], rw[i], rw[i+1])
// coarse4[j] = (ref[2j*COARSE], ref[(2j+1)*COARSE])            j < NC/2
__global__ __launch_bounds__(256) void bc_pack(
    const float* __restrict__ ref, const float* __restrict__ lw,
    const float* __restrict__ rw, float4* __restrict__ pairs,
    float4* __restrict__ wpair, float4* __restrict__ coarse4, int N)
{
    int i = blockIdx.x * 256 + threadIdx.x;
    const float2* __restrict__ ref2 = (const float2*)ref;
    if (i < N) {
        int i1 = (i + 1 == N) ? 0 : i + 1;
        float2 a = ref2[i], b = ref2[i1];
        pairs[i] = make_float4(a.x, a.y, b.x, b.y);
        wpair[i] = make_float4(lw[i], lw[i1], rw[i], rw[i1]);
    }
    int NC2 = N / (2 * COARSE);
    if (i < NC2) {
        float2 a = ref2[(2 * i) * COARSE];
        float2 b = ref2[(2 * i + 1) * COARSE];
        coarse4[i] = make_float4(a.x, a.y, b.x, b.y);
    }
}

__global__ __launch_bounds__(BLK, 8) void bc_fused(
    const float* __restrict__ pos, const float4* __restrict__ pairs,
    const float4* __restrict__ wpair, const float4* __restrict__ coarse4,
    const int* __restrict__ nit_p, float* __restrict__ out, int B, int N)
{
    int gtid = blockIdx.x * BLK + threadIdx.x;
    int q = gtid / LPQ;               // 16 consecutive lanes share a query
    int l = threadIdx.x & (LPQ - 1);  // lane-in-group
    if (q >= B) return;

    const float L = (float)N * DR_SAMP;
    float px = pos[2 * q], py = pos[2 * q + 1];  // group-broadcast loads

    // ---- coarse scan: 16 cands/lane via 8 float4 pair-loads ---------------
    // coarse4 is 2 KB total: L1-resident, ~4-line splits per instruction.
    int NCP = N / (2 * COARSE);  // packed pair count (128 for N=8192)
    unsigned int c0 = 0xFFFFFFFFu, c1 = 0xFFFFFFFFu;
    for (int j = l; j < NCP; j += 2 * LPQ) {
        float4 pa = coarse4[j];
        float4 pb = coarse4[j + LPQ];
        int ma = 2 * j * COARSE, mb = 2 * (j + LPQ) * COARSE;
        float dxa = px - pa.x, dya = py - pa.y;
        float dxb = px - pa.z, dyb = py - pa.w;
        c0 = min(c0, pack_key(fmaf(dxa, dxa, dya * dya), ma));
        c1 = min(c1, pack_key(fmaf(dxb, dxb, dyb * dyb), ma + COARSE));
        float dxc = px - pb.x, dyc = py - pb.y;
        float dxd = px - pb.z, dyd = py - pb.w;
        c0 = min(c0, pack_key(fmaf(dxc, dxc, dyc * dyc), mb));
        c1 = min(c1, pack_key(fmaf(dxd, dxd, dyd * dyd), mb + COARSE));
    }
    int jc = (int)(grp16_min(min(c0, c1)) & IDXMASK);

    // ---- fine exact scan: 64-wide window, 4 cands/lane via 2 pair-loads ---
    unsigned int fbest = 0xFFFFFFFFu;
    int base = jc - (WIN / 2 - 1);
#pragma unroll
    for (int t = 0; t < 2; ++t) {
        int ia = wrapN(base + 2 * l + t * 2 * LPQ, N);
        int ib = (ia + 1 == N) ? 0 : ia + 1;
        float4 pr = pairs[ia];
        float dxa = px - pr.x, dya = py - pr.y;
        float dxb = px - pr.z, dyb = py - pr.w;
        fbest = min(fbest, pack_key(fmaf(dxa, dxa, dya * dya), ia));
        fbest = min(fbest, pack_key(fmaf(dxb, dxb, dyb * dyb), ib));
    }
    fbest = grp16_min(fbest);
    float r = (float)(int)(fbest & IDXMASK) * DR_SAMP;

    // ---- Newton refinement: replicated across the 16 group lanes ----------
    // (same-address loads coalesce; ONE float4 load per iteration)
    int niter = nit_p[0];
    bool done = false;
    for (int it = 0; it < niter; ++it) {
        float fu = floorf(r);
        int i0 = (int)fu;
        if (i0 >= N) i0 -= N;
        float frac = r - fu;
        float4 pr = pairs[i0];
        float ex = pr.z - pr.x, ey = pr.w - pr.y;
        float ptx = fmaf(frac, ex, pr.x);
        float pty = fmaf(frac, ey, pr.y);
        float inv = rsqrtf(fmaf(ex, ex, ey * ey));
        float tx = ex * inv, ty = ey * inv;
        float dx = px - ptx, dy = py - pty;
        float fprime = -(dx * tx + dy * ty);
        float step = fminf(fmaxf(-fprime, -MAX_STEP), MAX_STEP);
        if (!done) {
            r += step;  // step in [-1,1] => r stays in (-1, L+1)
            if (r >= L) r -= L;
            if (r < 0.0f) r += L;
        }
        done = done || (fabsf(fprime) < TERM_EPS) || (fabsf(step) < TERM_DELTA_EPS);
    }

    // ---- final eval + outputs (lane 0 of each 16-lane group stores;
    //      active lanes' addresses are consecutive -> coalesced) ------------
    if (l != 0) return;

    float fu = floorf(r);
    int i0 = (int)fu;
    if (i0 >= N) i0 -= N;
    float frac = r - fu;
    float4 pr = pairs[i0];
    float4 wp = wpair[i0];
    float ex = pr.z - pr.x, ey = pr.w - pr.y;
    float ptx = fmaf(frac, ex, pr.x);
    float pty = fmaf(frac, ey, pr.y);
    float inv = rsqrtf(fmaf(ex, ex, ey * ey));
    float tx = ex * inv;
    float ty = ey * inv;
    float nx = -ty, ny = tx;
    float dx = px - ptx, dy = py - pty;
    float proj = dx * nx + dy * ny;
    float lv = wp.x * (1.0f - frac) + wp.y * frac;
    float rv = wp.z * (1.0f - frac) + wp.w * frac;

    out[q] = r;
    *(float2*)(out + B + 2 * q)     = make_float2(ptx, pty);
    *(float2*)(out + 3 * B + 2 * q) = make_float2(tx, ty);
    *(float2*)(out + 5 * B + 2 * q) = make_float2(nx, ny);
    *(float2*)(out + 7 * B + 2 * q) = make_float2(dx, dy);
    out[9 * B + q]  = proj;
    out[10 * B + q] = lv;
    out[11 * B + q] = rv;
}

extern "C" void kernel_launch(void* const* d_in, const int* in_sizes, int n_in,
                              void* d_out, int out_size, void* d_ws, size_t ws_size,
                              hipStream_t stream) {
    const float* pos = (const float*)d_in[0];
    const float* ref = (const float*)d_in[1];
    const float* lw  = (const float*)d_in[2];
    const float* rw  = (const float*)d_in[3];
    const int*   nit = (const int*)d_in[4];
    int B = in_sizes[0] / 2;
    int N = in_sizes[1] / 2;
    float* out = (float*)d_out;

    // d_ws layout (re-poisoned by harness each call -> rebuild each call):
    // pairs[N] float4 | wpair[N] float4 | coarse4[N/64] float4
    float4* pairs   = (float4*)d_ws;
    float4* wpair   = pairs + N;
    float4* coarse4 = wpair + N;

    int nbp = (N + 255) / 256;  // 32 blocks: trivially parallel pack
    bc_pack<<<nbp, 256, 0, stream>>>(ref, lw, rw, pairs, wpair, coarse4, N);

    // 16 lanes/query, BLK=256 -> 2048 blocks = 8 blocks/CU = 32 waves/CU.
    long long threads = (long long)B * LPQ;
    int nb = (int)((threads + BLK - 1) / BLK);
    bc_fused<<<nb, BLK, 0, stream>>>(pos, pairs, wpair, coarse4, nit, out, B, N);
}

// Round 7
// 69.052 us; speedup vs baseline: 1.0266x; 1.0250x over previous
//
#include <hip/hip_runtime.h>
#include <math.h>

// BoundsChecker: nearest-point-on-closed-path + Newton refine + frame/width
// outputs. Pack kernel (float4 lookup tables in d_ws) + main kernel
// (16 lanes/query, no LDS, no barrier) + EARLY-EXIT NEWTON.
//
// Ledger (rounds 1-6): totals 131/89.5/80.4/70.4/70.9/70.8 all fit
// total = kernel + ~65.5 us harness floor (256 MB d_ws poison = 40 us at
// 84% HBM peak + restores/small fills/graph gaps). bc_fused is now ~5 us.
// r7 change: Newton loop exits when ALL 64 lanes are done (exact: done is
// monotone and masked updates are no-ops after convergence; starting from
// the exact argmin sample, convergence is 1-2 iters, so this cuts the
// dependent load+VALU chain ~65%). If total doesn't move, the kernel is
// <=3 us and the session is harness-floor-bound.
//
// Inputs: positions[B,2] f32, refline_points[N,2] f32, left_widths[N] f32,
//         right_widths[N] f32, newton_iterations (int scalar in device mem).
// Output (flat concat, f32): r[B], point[B,2], tang[B,2], norm[B,2],
//         deltas[B,2], normal_projections[B], left[B], right[B] (12*B total).

#define DR_SAMP 1.0f
#define MAX_STEP 1.0f
#define TERM_EPS 1e-4f
#define TERM_DELTA_EPS 1e-2f

#define COARSE 32      // coarse stride (samples)
#define WIN 64         // fine window width (coarse best provably within +-17)
#define BLK 256
#define LPQ 16         // lanes per query -> B*16 threads, 2048 blocks

// Packed argmin key: top 19 bits of float(d2) | 13-bit index (N <= 8192).
// d2 >= 0 so float bits order as unsigned. Near-tie mis-ordering is absorbed
// by Newton (passed rounds 1-6 with absmax 0.031).
#define IDXBITS 13
#define IDXMASK ((1u << IDXBITS) - 1u)
#define KEYMASK (~IDXMASK)

__device__ __forceinline__ unsigned int pack_key(float d2, int i) {
    return (__float_as_uint(d2) & KEYMASK) | (unsigned int)i;
}

__device__ __forceinline__ int wrapN(int i, int N) {
    return (i < 0) ? i + N : ((i >= N) ? i - N : i);
}

// butterfly min over each aligned 16-lane group (xor 1,2,4,8 stays in-group)
__device__ __forceinline__ unsigned int grp16_min(unsigned int k) {
    k = min(k, (unsigned int)__shfl_xor((int)k, 1));
    k = min(k, (unsigned int)__shfl_xor((int)k, 2));
    k = min(k, (unsigned int)__shfl_xor((int)k, 4));
    k = min(k, (unsigned int)__shfl_xor((int)k, 8));
    return k;
}

// ---- pack kernel: build float4 lookup tables in d_ws --------------------
// pairs[i]   = (ref[i].x, ref[i].y, ref[i+1].x, ref[i+1].y)   (i+1 mod N)
// wpair[i]   = (lw[i], lw[i+1], rw[i], rw[i+1])
// coarse4[j] = (ref[2j*COARSE], ref[(2j+1)*COARSE])            j < NC/2
__global__ __launch_bounds__(256) void bc_pack(
    const float* __restrict__ ref, const float* __restrict__ lw,
    const float* __restrict__ rw, float4* __restrict__ pairs,
    float4* __restrict__ wpair, float4* __restrict__ coarse4, int N)
{
    int i = blockIdx.x * 256 + threadIdx.x;
    const float2* __restrict__ ref2 = (const float2*)ref;
    if (i < N) {
        int i1 = (i + 1 == N) ? 0 : i + 1;
        float2 a = ref2[i], b = ref2[i1];
        pairs[i] = make_float4(a.x, a.y, b.x, b.y);
        wpair[i] = make_float4(lw[i], lw[i1], rw[i], rw[i1]);
    }
    int NC2 = N / (2 * COARSE);
    if (i < NC2) {
        float2 a = ref2[(2 * i) * COARSE];
        float2 b = ref2[(2 * i + 1) * COARSE];
        coarse4[i] = make_float4(a.x, a.y, b.x, b.y);
    }
}

__global__ __launch_bounds__(BLK, 8) void bc_fused(
    const float* __restrict__ pos, const float4* __restrict__ pairs,
    const float4* __restrict__ wpair, const float4* __restrict__ coarse4,
    const int* __restrict__ nit_p, float* __restrict__ out, int B, int N)
{
    int gtid = blockIdx.x * BLK + threadIdx.x;
    int q = gtid / LPQ;               // 16 consecutive lanes share a query
    int l = threadIdx.x & (LPQ - 1);  // lane-in-group
    if (q >= B) return;

    int niter = nit_p[0];             // scalar load, issued early

    const float L = (float)N * DR_SAMP;
    float px = pos[2 * q], py = pos[2 * q + 1];  // group-broadcast loads

    // ---- coarse scan: 16 cands/lane via 8 float4 pair-loads ---------------
    // coarse4 is 2 KB total: L1-resident after first touch per CU.
    int NCP = N / (2 * COARSE);  // packed pair count (128 for N=8192)
    unsigned int c0 = 0xFFFFFFFFu, c1 = 0xFFFFFFFFu;
    for (int j = l; j < NCP; j += 2 * LPQ) {
        float4 pa = coarse4[j];
        float4 pb = coarse4[j + LPQ];
        int ma = 2 * j * COARSE, mb = 2 * (j + LPQ) * COARSE;
        float dxa = px - pa.x, dya = py - pa.y;
        float dxb = px - pa.z, dyb = py - pa.w;
        c0 = min(c0, pack_key(fmaf(dxa, dxa, dya * dya), ma));
        c1 = min(c1, pack_key(fmaf(dxb, dxb, dyb * dyb), ma + COARSE));
        float dxc = px - pb.x, dyc = py - pb.y;
        float dxd = px - pb.z, dyd = py - pb.w;
        c0 = min(c0, pack_key(fmaf(dxc, dxc, dyc * dyc), mb));
        c1 = min(c1, pack_key(fmaf(dxd, dxd, dyd * dyd), mb + COARSE));
    }
    int jc = (int)(grp16_min(min(c0, c1)) & IDXMASK);

    // ---- fine exact scan: 64-wide window, 4 cands/lane via 2 pair-loads ---
    unsigned int fbest = 0xFFFFFFFFu;
    int base = jc - (WIN / 2 - 1);
#pragma unroll
    for (int t = 0; t < 2; ++t) {
        int ia = wrapN(base + 2 * l + t * 2 * LPQ, N);
        int ib = (ia + 1 == N) ? 0 : ia + 1;
        float4 pr = pairs[ia];
        float dxa = px - pr.x, dya = py - pr.y;
        float dxb = px - pr.z, dyb = py - pr.w;
        fbest = min(fbest, pack_key(fmaf(dxa, dxa, dya * dya), ia));
        fbest = min(fbest, pack_key(fmaf(dxb, dxb, dyb * dyb), ib));
    }
    fbest = grp16_min(fbest);
    float r = (float)(int)(fbest & IDXMASK) * DR_SAMP;

    // ---- Newton refinement: replicated across the 16 group lanes ----------
    // Loads hit L1 (fine scan just touched this window). EARLY EXIT when all
    // 64 lanes are done -- exact: done is monotone and post-done iterations
    // are masked no-ops in the reference.
    bool done = false;
    for (int it = 0; it < niter; ++it) {
        float fu = floorf(r);
        int i0 = (int)fu;
        if (i0 >= N) i0 -= N;
        float frac = r - fu;
        float4 pr = pairs[i0];
        float ex = pr.z - pr.x, ey = pr.w - pr.y;
        float ptx = fmaf(frac, ex, pr.x);
        float pty = fmaf(frac, ey, pr.y);
        float inv = rsqrtf(fmaf(ex, ex, ey * ey));
        float tx = ex * inv, ty = ey * inv;
        float dx = px - ptx, dy = py - pty;
        float fprime = -(dx * tx + dy * ty);
        float step = fminf(fmaxf(-fprime, -MAX_STEP), MAX_STEP);
        if (!done) {
            r += step;  // step in [-1,1] => r stays in (-1, L+1)
            if (r >= L) r -= L;
            if (r < 0.0f) r += L;
        }
        done = done || (fabsf(fprime) < TERM_EPS) || (fabsf(step) < TERM_DELTA_EPS);
        if (__all(done)) break;   // wave-uniform exit, typically after 1-2 iters
    }

    // ---- final eval + outputs (lane 0 of each 16-lane group stores;
    //      active lanes' addresses are consecutive -> coalesced) ------------
    if (l != 0) return;

    float fu = floorf(r);
    int i0 = (int)fu;
    if (i0 >= N) i0 -= N;
    float frac = r - fu;
    float4 pr = pairs[i0];
    float4 wp = wpair[i0];
    float ex = pr.z - pr.x, ey = pr.w - pr.y;
    float ptx = fmaf(frac, ex, pr.x);
    float pty = fmaf(frac, ey, pr.y);
    float inv = rsqrtf(fmaf(ex, ex, ey * ey));
    float tx = ex * inv;
    float ty = ey * inv;
    float nx = -ty, ny = tx;
    float dx = px - ptx, dy = py - pty;
    float proj = dx * nx + dy * ny;
    float lv = wp.x * (1.0f - frac) + wp.y * frac;
    float rv = wp.z * (1.0f - frac) + wp.w * frac;

    out[q] = r;
    *(float2*)(out + B + 2 * q)     = make_float2(ptx, pty);
    *(float2*)(out + 3 * B + 2 * q) = make_float2(tx, ty);
    *(float2*)(out + 5 * B + 2 * q) = make_float2(nx, ny);
    *(float2*)(out + 7 * B + 2 * q) = make_float2(dx, dy);
    out[9 * B + q]  = proj;
    out[10 * B + q] = lv;
    out[11 * B + q] = rv;
}

extern "C" void kernel_launch(void* const* d_in, const int* in_sizes, int n_in,
                              void* d_out, int out_size, void* d_ws, size_t ws_size,
                              hipStream_t stream) {
    const float* pos = (const float*)d_in[0];
    const float* ref = (const float*)d_in[1];
    const float* lw  = (const float*)d_in[2];
    const float* rw  = (const float*)d_in[3];
    const int*   nit = (const int*)d_in[4];
    int B = in_sizes[0] / 2;
    int N = in_sizes[1] / 2;
    float* out = (float*)d_out;

    // d_ws layout (re-poisoned by harness each call -> rebuild each call):
    // pairs[N] float4 | wpair[N] float4 | coarse4[N/64] float4
    float4* pairs   = (float4*)d_ws;
    float4* wpair   = pairs + N;
    float4* coarse4 = wpair + N;

    int nbp = (N + 255) / 256;  // 32 blocks: trivially parallel pack
    bc_pack<<<nbp, 256, 0, stream>>>(ref, lw, rw, pairs, wpair, coarse4, N);

    // 16 lanes/query, BLK=256 -> 2048 blocks = 8 blocks/CU = 32 waves/CU.
    long long threads = (long long)B * LPQ;
    int nb = (int)((threads + BLK - 1) / BLK);
    bc_fused<<<nb, BLK, 0, stream>>>(pos, pairs, wpair, coarse4, nit, out, B, N);
}